// Round 6
// baseline (854.889 us; speedup 1.0000x reference)
//
#include <hip/hip_runtime.h>
#include <hip/hip_fp16.h>
#include <cmath>

#define NN 100000
#define EE 1600000
#define TOTE (EE + NN)
#define SHIFT 10
#define NBUK 98          // ceil(NN / 1024)
#define CAPB 18432       // per-bucket region capacity; mean 17408 +7 sigma

typedef _Float16 half8_t __attribute__((ext_vector_type(8)));
typedef _Float16 half4_t __attribute__((ext_vector_type(4)));
typedef _Float16 half2_t __attribute__((ext_vector_type(2)));
typedef float float4_t __attribute__((ext_vector_type(4)));

__device__ __forceinline__ float lrelu(float v) { return v > 0.f ? v : 0.2f * v; }

// ---------------- CSR build: 2-phase bucket sort ----------------
__global__ __launch_bounds__(256) void binA(const int* __restrict__ src, const int* __restrict__ dst,
                                            int* __restrict__ gcur, int* __restrict__ region) {
    __shared__ int cnt[NBUK], gbase[NBUK], pos[NBUK];
    int t = threadIdx.x;
    if (t < NBUK) cnt[t] = 0;
    __syncthreads();
    const int CH = (TOTE + gridDim.x - 1) / gridDim.x;
    int lo = blockIdx.x * CH;
    int hi = lo + CH; if (hi > TOTE) hi = TOTE;
    for (int e = lo + t; e < hi; e += 256) {
        int d = (e < EE) ? dst[e] : (e - EE);
        atomicAdd(&cnt[d >> SHIFT], 1);
    }
    __syncthreads();
    if (t < NBUK) {
        gbase[t] = atomicAdd(&gcur[t], cnt[t]);
        pos[t] = 0;
    }
    __syncthreads();
    for (int e = lo + t; e < hi; e += 256) {
        int s, d;
        if (e < EE) { s = src[e]; d = dst[e]; }
        else        { s = e - EE; d = s; }
        int b = d >> SHIFT;
        int k = atomicAdd(&pos[b], 1);
        region[(size_t)b * CAPB + gbase[b] + k] = (s << SHIFT) | (d & 1023);
    }
}

__global__ void scan_buckets(const int* __restrict__ gcur, int* __restrict__ bucketBase) {
    if (threadIdx.x == 0) {
        int run = 0;
        for (int b = 0; b < NBUK; ++b) { bucketBase[b] = run; run += gcur[b]; }
        bucketBase[NBUK] = run;
    }
}

__global__ __launch_bounds__(1024) void binB(const int* __restrict__ region, const int* __restrict__ gcur,
                                             const int* __restrict__ bucketBase,
                                             int* __restrict__ dst_ptr, int* __restrict__ esrc) {
    __shared__ int ncur[1024];
    __shared__ int wsum[16];
    int b = blockIdx.x, t = threadIdx.x;
    int n0 = b << SHIFT;
    int cntE = gcur[b];
    int base = bucketBase[b];
    const int* reg = region + (size_t)b * CAPB;
    ncur[t] = 0;
    __syncthreads();
    for (int i = t; i < cntE; i += 1024)
        atomicAdd(&ncur[reg[i] & 1023], 1);
    __syncthreads();
    int v = ncur[t];
    __syncthreads();
    int incl = v;
    for (int off = 1; off < 64; off <<= 1) {
        int u = __shfl_up(incl, off);
        if ((t & 63) >= off) incl += u;
    }
    if ((t & 63) == 63) wsum[t >> 6] = incl;
    __syncthreads();
    if (t < 16) {
        int w = wsum[t];
        int winc = w;
        for (int off = 1; off < 16; off <<= 1) {
            int u = __shfl_up(winc, off);
            if (t >= off) winc += u;
        }
        wsum[t] = winc - w;
    }
    __syncthreads();
    int excl = incl - v + wsum[t >> 6];
    int n = n0 + t;
    if (n < NN) dst_ptr[n] = base + excl;
    ncur[t] = base + excl;
    __syncthreads();
    for (int i = t; i < cntE; i += 1024) {
        int p = reg[i];
        int k = atomicAdd(&ncur[p & 1023], 1);
        esrc[k] = p >> SHIFT;
    }
    if (b == 0 && t == 0) dst_ptr[NN] = TOTE;
}

// ---------------- f32 -> f16 cast of node_attrs ----------------
__global__ __launch_bounds__(256) void cast_x(const float* __restrict__ in, _Float16* __restrict__ out, int n4) {
    int i = blockIdx.x * 256 + threadIdx.x;
    if (i >= n4) return;
    float4 v = ((const float4*)in)[i];
    half4_t h = { (_Float16)v.x, (_Float16)v.y, (_Float16)v.z, (_Float16)v.w };
    *(half4_t*)(out + 4 * (size_t)i) = h;
}

// ---------------- MFMA GEMM + fused attention coefficients ----------------
template <int K>
__global__ __launch_bounds__(256) void gemm_attn(const _Float16* __restrict__ X, const float* __restrict__ W,
                                                 const float* __restrict__ a_src, const float* __restrict__ a_dst,
                                                 _Float16* __restrict__ H, float* __restrict__ asrc,
                                                 float* __restrict__ adst) {
    __shared__ _Float16 wt[64][K + 8];    // wt[n][k], padded stride
    int t = threadIdx.x;
    for (int it = 0; it < K / 16; ++it) {
        int idx4 = it * 256 + t;
        int k = idx4 >> 4;
        int n4 = (idx4 * 4) & 63;
        float4 v = *(const float4*)(W + (size_t)idx4 * 4);
        wt[n4 + 0][k] = (_Float16)v.x;
        wt[n4 + 1][k] = (_Float16)v.y;
        wt[n4 + 2][k] = (_Float16)v.z;
        wt[n4 + 3][k] = (_Float16)v.w;
    }
    __syncthreads();

    int row0 = blockIdx.x * 64;
    int wr = (t >> 6) * 16;
    int lane = t & 63;
    int m = lane & 15;
    int q = lane >> 4;

    int rowA = row0 + wr + m;
    if (rowA >= NN) rowA = NN - 1;
    const _Float16* xrow = X + (size_t)rowA * K + q * 8;

    float4_t acc[4] = { {0,0,0,0}, {0,0,0,0}, {0,0,0,0}, {0,0,0,0} };
#pragma unroll
    for (int kc = 0; kc < K / 32; ++kc) {
        half8_t av = *(const half8_t*)(xrow + kc * 32);
#pragma unroll
        for (int c = 0; c < 4; ++c) {
            half8_t bv = *(const half8_t*)&wt[c * 16 + m][kc * 32 + q * 8];
            acc[c] = __builtin_amdgcn_mfma_f32_16x16x32_f16(av, bv, acc[c], 0, 0, 0);
        }
    }

#pragma unroll
    for (int r = 0; r < 4; ++r) {
        int row = row0 + wr + q * 4 + r;
        if (row < NN) {
#pragma unroll
            for (int c = 0; c < 4; ++c)
                H[(size_t)row * 64 + c * 16 + m] = (_Float16)acc[c][r];
        }
    }

    float as0 = a_src[m], as1 = a_src[16 + m], as2 = a_src[32 + m], as3 = a_src[48 + m];
    float ad0 = a_dst[m], ad1 = a_dst[16 + m], ad2 = a_dst[32 + m], ad3 = a_dst[48 + m];
#pragma unroll
    for (int r = 0; r < 4; ++r) {
        float s0 = acc[0][r] * as0 + acc[1][r] * as1;
        float s1 = acc[2][r] * as2 + acc[3][r] * as3;
        float d0 = acc[0][r] * ad0 + acc[1][r] * ad1;
        float d1 = acc[2][r] * ad2 + acc[3][r] * ad3;
#pragma unroll
        for (int mk = 1; mk < 16; mk <<= 1) {
            s0 += __shfl_xor(s0, mk);
            s1 += __shfl_xor(s1, mk);
            d0 += __shfl_xor(d0, mk);
            d1 += __shfl_xor(d1, mk);
        }
        int row = row0 + wr + q * 4 + r;
        if (m == 0 && row < NN) {
            asrc[2 * row + 0] = s0;
            asrc[2 * row + 1] = s1;
            adst[2 * row + 0] = d0;
            adst[2 * row + 1] = d1;
        }
    }
}

// ---------------- per-edge normalized softmax weights (both heads, fp16) ------
// Wave per node; lanes over edges. Two passes (recompute) -> alpha = p/l.
__global__ __launch_bounds__(256) void calc_alpha(const int* __restrict__ dst_ptr, const int* __restrict__ esrc,
                                                  const float* __restrict__ asrc, const float* __restrict__ adst,
                                                  _Float16* __restrict__ alpha) {
    int n = (blockIdx.x * 256 + threadIdx.x) >> 6;
    if (n >= NN) return;
    int lane = threadIdx.x & 63;
    int rs = dst_ptr[n], re = dst_ptr[n + 1];
    float ad0 = adst[2 * n], ad1 = adst[2 * n + 1];
    float l0 = 0.f, l1 = 0.f;
    for (int i = rs + lane; i < re; i += 64) {
        int s = esrc[i];
        float2 as = *(const float2*)(asrc + 2 * s);
        l0 += __expf(fminf(lrelu(as.x + ad0), 60.f));
        l1 += __expf(fminf(lrelu(as.y + ad1), 60.f));
    }
    for (int mm = 32; mm >= 1; mm >>= 1) {
        l0 += __shfl_xor(l0, mm);
        l1 += __shfl_xor(l1, mm);
    }
    float inv0 = 1.f / l0, inv1 = 1.f / l1;
    for (int i = rs + lane; i < re; i += 64) {
        int s = esrc[i];
        float2 as = *(const float2*)(asrc + 2 * s);
        float p0 = __expf(fminf(lrelu(as.x + ad0), 60.f)) * inv0;
        float p1 = __expf(fminf(lrelu(as.y + ad1), 60.f)) * inv1;
        half2_t a = { (_Float16)p0, (_Float16)p1 };
        *(half2_t*)(alpha + 2 * (size_t)i) = a;
    }
}

// ---------------- edge aggregation: pure alpha-weighted gather ----------------
// Wave per node. lane = eo*16 + c4: eo = edge slot (4-way), c4 = channel quad.
// 8 edges in flight per iteration. acc[4] f32 per lane.
template <int MODE>
__global__ __launch_bounds__(256) void edge_agg(const int* __restrict__ dst_ptr, const int* __restrict__ esrc,
                                                const _Float16* __restrict__ h, const _Float16* __restrict__ alpha,
                                                const float* __restrict__ bias,
                                                const float* __restrict__ init_in, float* __restrict__ init_out,
                                                _Float16* __restrict__ xout) {
    int n = (blockIdx.x * 256 + threadIdx.x) >> 6;
    if (n >= NN) return;
    int lane = threadIdx.x & 63;
    int eo = lane >> 4;
    int c4 = lane & 15;
    int head = c4 >> 3;
    int rs = dst_ptr[n], re = dst_ptr[n + 1];
    const _Float16* hb = h + 4 * c4;
    float a0 = 0.f, a1 = 0.f, a2 = 0.f, a3 = 0.f;
    for (int i = rs; i < re; i += 8) {
        int iA = i + eo;
        int iB = i + 4 + eo;
        int cA = iA < re ? iA : re - 1;
        int cB = iB < re ? iB : re - 1;
        int sA = esrc[cA];
        int sB = esrc[cB];
        float wA = (float)alpha[2 * (size_t)cA + head];
        float wB = (float)alpha[2 * (size_t)cB + head];
        half4_t hA = *(const half4_t*)(hb + (size_t)sA * 64);
        half4_t hB = *(const half4_t*)(hb + (size_t)sB * 64);
        wA = iA < re ? wA : 0.f;
        wB = iB < re ? wB : 0.f;
        a0 += wA * (float)hA[0] + wB * (float)hB[0];
        a1 += wA * (float)hA[1] + wB * (float)hB[1];
        a2 += wA * (float)hA[2] + wB * (float)hB[2];
        a3 += wA * (float)hA[3] + wB * (float)hB[3];
    }
    // merge the 4 edge slots
    a0 += __shfl_xor(a0, 16); a1 += __shfl_xor(a1, 16);
    a2 += __shfl_xor(a2, 16); a3 += __shfl_xor(a3, 16);
    a0 += __shfl_xor(a0, 32); a1 += __shfl_xor(a1, 32);
    a2 += __shfl_xor(a2, 32); a3 += __shfl_xor(a3, 32);
    if (eo == 0) {
        float4 bv = *(const float4*)(bias + 4 * c4);
        float t0 = a0 + bv.x, t1 = a1 + bv.y, t2 = a2 + bv.z, t3 = a3 + bv.w;
        if (MODE == 0) {
            *(float4*)(init_out + (size_t)n * 64 + 4 * c4) = make_float4(t0, t1, t2, t3);
        } else {
            float4 iv = *(const float4*)(init_in + (size_t)n * 64 + 4 * c4);
            t0 += iv.x; t1 += iv.y; t2 += iv.z; t3 += iv.w;
        }
        t0 = t0 > 0.f ? t0 : __expf(t0) - 1.f;
        t1 = t1 > 0.f ? t1 : __expf(t1) - 1.f;
        t2 = t2 > 0.f ? t2 : __expf(t2) - 1.f;
        t3 = t3 > 0.f ? t3 : __expf(t3) - 1.f;
        half4_t o = { (_Float16)t0, (_Float16)t1, (_Float16)t2, (_Float16)t3 };
        *(half4_t*)(xout + (size_t)n * 64 + 4 * c4) = o;
    }
}

// ---------------- output layer ----------------
__global__ __launch_bounds__(256) void gemm_out_attn(const _Float16* __restrict__ x, const float* __restrict__ Wout,
                                                     const float* __restrict__ a_s, const float* __restrict__ a_d,
                                                     float* __restrict__ h_o, float* __restrict__ asrc_o,
                                                     float* __restrict__ adst_o) {
    int n = (blockIdx.x * 256 + threadIdx.x) >> 6;
    if (n >= NN) return;
    int lane = threadIdx.x & 63;
    float v = (float)x[n * 64 + lane] * Wout[lane];
    for (int m = 32; m >= 1; m >>= 1) v += __shfl_xor(v, m);
    if (lane == 0) {
        h_o[n] = v;
        asrc_o[n] = v * a_s[0];
        adst_o[n] = v * a_d[0];
    }
}

__global__ __launch_bounds__(256) void edge_agg_out(const int* __restrict__ dst_ptr, const int* __restrict__ esrc,
                                                    const float* __restrict__ h_o, const float* __restrict__ asrc_o,
                                                    const float* __restrict__ adst_o, const float* __restrict__ b_out,
                                                    float* __restrict__ out) {
    int n = (blockIdx.x * 256 + threadIdx.x) >> 6;
    if (n >= NN) return;
    int lane = threadIdx.x & 63;
    int rs = dst_ptr[n], re = dst_ptr[n + 1];
    float adv = adst_o[n];
    float l = 0.f, acc = 0.f;
    for (int i = rs + lane; i < re; i += 64) {
        int s = esrc[i];
        float e = fminf(lrelu(asrc_o[s] + adv), 60.f);
        float p = __expf(e);
        l += p;
        acc = fmaf(p, h_o[s], acc);
    }
    for (int mm = 32; mm >= 1; mm >>= 1) {
        l += __shfl_xor(l, mm);
        acc += __shfl_xor(acc, mm);
    }
    if (lane == 0) out[n] = 1.f / (1.f + __expf(-(acc / l + b_out[0])));
}

// ---------------- launch ----------------
extern "C" void kernel_launch(void* const* d_in, const int* in_sizes, int n_in,
                              void* d_out, int out_size, void* d_ws, size_t ws_size,
                              hipStream_t stream) {
    const float* node_attrs = (const float*)d_in[0];
    const int*   edge_index = (const int*)d_in[1];
    const float* W_in      = (const float*)d_in[2];
    const float* a_src_in  = (const float*)d_in[3];
    const float* a_dst_in  = (const float*)d_in[4];
    const float* b_in      = (const float*)d_in[5];
    const float* W_mid     = (const float*)d_in[6];
    const float* a_src_mid = (const float*)d_in[7];
    const float* a_dst_mid = (const float*)d_in[8];
    const float* b_mid     = (const float*)d_in[9];
    const float* W_out     = (const float*)d_in[10];
    const float* a_src_out = (const float*)d_in[11];
    const float* a_dst_out = (const float*)d_in[12];
    const float* b_out     = (const float*)d_in[13];
    float* out = (float*)d_out;

    const int* srcArr = edge_index;
    const int* dstArr = edge_index + EE;

    char* w = (char*)d_ws;
    auto alloc = [&](size_t bytes) { void* p = (void*)w; w += (bytes + 255) & ~(size_t)255; return p; };
    int*   dst_ptr    = (int*)alloc((size_t)(NN + 1) * 4);
    int*   gcur       = (int*)alloc((size_t)NBUK * 4);
    int*   bucketBase = (int*)alloc((size_t)(NBUK + 1) * 4);
    int*   region     = (int*)alloc((size_t)NBUK * CAPB * 4);
    int*   esrc       = (int*)alloc((size_t)TOTE * 4);
    _Float16* alpha   = (_Float16*)alloc((size_t)TOTE * 2 * 2);
    _Float16* xin16   = (_Float16*)alloc((size_t)NN * 128 * 2);
    _Float16* h       = (_Float16*)alloc((size_t)NN * 64 * 2);
    _Float16* x16     = (_Float16*)alloc((size_t)NN * 64 * 2);
    float* asrc       = (float*)alloc((size_t)NN * 2 * 4);
    float* adst       = (float*)alloc((size_t)NN * 2 * 4);
    float* ixbuf      = (float*)alloc((size_t)NN * 64 * 4);
    float* h_o        = (float*)alloc((size_t)NN * 4);
    float* asrc_o     = (float*)alloc((size_t)NN * 4);
    float* adst_o     = (float*)alloc((size_t)NN * 4);

    // CSR build
    hipMemsetAsync(gcur, 0, NBUK * 4, stream);
    binA<<<256, 256, 0, stream>>>(srcArr, dstArr, gcur, region);
    scan_buckets<<<1, 64, 0, stream>>>(gcur, bucketBase);
    binB<<<NBUK, 1024, 0, stream>>>(region, gcur, bucketBase, dst_ptr, esrc);

    // cast node_attrs to f16
    int n4 = NN * 128 / 4;
    cast_x<<<(n4 + 255) / 256, 256, 0, stream>>>(node_attrs, xin16, n4);

    int gemmBlocks = (NN + 63) / 64;
    int nodeBlocks = (NN + 3) / 4;

    // input layer
    gemm_attn<128><<<gemmBlocks, 256, 0, stream>>>(xin16, W_in, a_src_in, a_dst_in, h, asrc, adst);
    calc_alpha<<<nodeBlocks, 256, 0, stream>>>(dst_ptr, esrc, asrc, adst, alpha);
    edge_agg<0><<<nodeBlocks, 256, 0, stream>>>(dst_ptr, esrc, h, alpha, b_in, nullptr, ixbuf, x16);

    // 6 mid layers (shared weights)
    for (int l = 0; l < 6; ++l) {
        gemm_attn<64><<<gemmBlocks, 256, 0, stream>>>(x16, W_mid, a_src_mid, a_dst_mid, h, asrc, adst);
        calc_alpha<<<nodeBlocks, 256, 0, stream>>>(dst_ptr, esrc, asrc, adst, alpha);
        edge_agg<1><<<nodeBlocks, 256, 0, stream>>>(dst_ptr, esrc, h, alpha, b_mid, ixbuf, nullptr, x16);
    }

    // output layer
    gemm_out_attn<<<nodeBlocks, 256, 0, stream>>>(x16, W_out, a_src_out, a_dst_out, h_o, asrc_o, adst_o);
    edge_agg_out<<<nodeBlocks, 256, 0, stream>>>(dst_ptr, esrc, h_o, asrc_o, adst_o, b_out, out);
}

// Round 7
// 740.792 us; speedup vs baseline: 1.1540x; 1.1540x over previous
//
#include <hip/hip_runtime.h>
#include <hip/hip_fp16.h>
#include <cmath>

#define NN 100000
#define EE 1600000
#define TOTE (EE + NN)
#define SHIFT 10
#define NBUK 98          // ceil(NN / 1024)
#define CAPB 18432       // per-bucket region capacity; mean 17408 +7 sigma

typedef _Float16 half8_t __attribute__((ext_vector_type(8)));
typedef _Float16 half4_t __attribute__((ext_vector_type(4)));
typedef _Float16 half2_t __attribute__((ext_vector_type(2)));
typedef float float4_t __attribute__((ext_vector_type(4)));

__device__ __forceinline__ float lrelu(float v) { return v > 0.f ? v : 0.2f * v; }

// ---------------- CSR build: 2-phase bucket sort ----------------
__global__ __launch_bounds__(256) void binA(const int* __restrict__ src, const int* __restrict__ dst,
                                            int* __restrict__ gcur, int* __restrict__ region) {
    __shared__ int cnt[NBUK], gbase[NBUK], pos[NBUK];
    int t = threadIdx.x;
    if (t < NBUK) cnt[t] = 0;
    __syncthreads();
    const int CH = (TOTE + gridDim.x - 1) / gridDim.x;
    int lo = blockIdx.x * CH;
    int hi = lo + CH; if (hi > TOTE) hi = TOTE;
    for (int e = lo + t; e < hi; e += 256) {
        int d = (e < EE) ? dst[e] : (e - EE);
        atomicAdd(&cnt[d >> SHIFT], 1);
    }
    __syncthreads();
    if (t < NBUK) {
        gbase[t] = atomicAdd(&gcur[t], cnt[t]);
        pos[t] = 0;
    }
    __syncthreads();
    for (int e = lo + t; e < hi; e += 256) {
        int s, d;
        if (e < EE) { s = src[e]; d = dst[e]; }
        else        { s = e - EE; d = s; }
        int b = d >> SHIFT;
        int k = atomicAdd(&pos[b], 1);
        region[(size_t)b * CAPB + gbase[b] + k] = (s << SHIFT) | (d & 1023);
    }
}

__global__ void scan_buckets(const int* __restrict__ gcur, int* __restrict__ bucketBase) {
    if (threadIdx.x == 0) {
        int run = 0;
        for (int b = 0; b < NBUK; ++b) { bucketBase[b] = run; run += gcur[b]; }
        bucketBase[NBUK] = run;
    }
}

__global__ __launch_bounds__(1024) void binB(const int* __restrict__ region, const int* __restrict__ gcur,
                                             const int* __restrict__ bucketBase,
                                             int* __restrict__ dst_ptr, int* __restrict__ esrc,
                                             int* __restrict__ edst) {
    __shared__ int ncur[1024];
    __shared__ int wsum[16];
    int b = blockIdx.x, t = threadIdx.x;
    int n0 = b << SHIFT;
    int cntE = gcur[b];
    int base = bucketBase[b];
    const int* reg = region + (size_t)b * CAPB;
    ncur[t] = 0;
    __syncthreads();
    for (int i = t; i < cntE; i += 1024)
        atomicAdd(&ncur[reg[i] & 1023], 1);
    __syncthreads();
    int v = ncur[t];
    __syncthreads();
    int incl = v;
    for (int off = 1; off < 64; off <<= 1) {
        int u = __shfl_up(incl, off);
        if ((t & 63) >= off) incl += u;
    }
    if ((t & 63) == 63) wsum[t >> 6] = incl;
    __syncthreads();
    if (t < 16) {
        int w = wsum[t];
        int winc = w;
        for (int off = 1; off < 16; off <<= 1) {
            int u = __shfl_up(winc, off);
            if (t >= off) winc += u;
        }
        wsum[t] = winc - w;
    }
    __syncthreads();
    int excl = incl - v + wsum[t >> 6];
    int n = n0 + t;
    if (n < NN) dst_ptr[n] = base + excl;
    ncur[t] = base + excl;
    __syncthreads();
    for (int i = t; i < cntE; i += 1024) {
        int p = reg[i];
        int local = p & 1023;
        int k = atomicAdd(&ncur[local], 1);
        esrc[k] = p >> SHIFT;
        edst[k] = n0 + local;
    }
    if (b == 0 && t == 0) dst_ptr[NN] = TOTE;
}

// ---------------- f32 -> f16 cast of node_attrs ----------------
__global__ __launch_bounds__(256) void cast_x(const float* __restrict__ in, _Float16* __restrict__ out, int n4) {
    int i = blockIdx.x * 256 + threadIdx.x;
    if (i >= n4) return;
    float4 v = ((const float4*)in)[i];
    half4_t h = { (_Float16)v.x, (_Float16)v.y, (_Float16)v.z, (_Float16)v.w };
    *(half4_t*)(out + 4 * (size_t)i) = h;
}

// ---------------- MFMA GEMM + fused attention coefficients ----------------
template <int K>
__global__ __launch_bounds__(256) void gemm_attn(const _Float16* __restrict__ X, const float* __restrict__ W,
                                                 const float* __restrict__ a_src, const float* __restrict__ a_dst,
                                                 _Float16* __restrict__ H, float* __restrict__ asrc,
                                                 float* __restrict__ adst) {
    __shared__ _Float16 wt[64][K + 8];    // wt[n][k], padded stride
    int t = threadIdx.x;
    for (int it = 0; it < K / 16; ++it) {
        int idx4 = it * 256 + t;
        int k = idx4 >> 4;
        int n4 = (idx4 * 4) & 63;
        float4 v = *(const float4*)(W + (size_t)idx4 * 4);
        wt[n4 + 0][k] = (_Float16)v.x;
        wt[n4 + 1][k] = (_Float16)v.y;
        wt[n4 + 2][k] = (_Float16)v.z;
        wt[n4 + 3][k] = (_Float16)v.w;
    }
    __syncthreads();

    int row0 = blockIdx.x * 64;
    int wr = (t >> 6) * 16;
    int lane = t & 63;
    int m = lane & 15;
    int q = lane >> 4;

    int rowA = row0 + wr + m;
    if (rowA >= NN) rowA = NN - 1;
    const _Float16* xrow = X + (size_t)rowA * K + q * 8;

    float4_t acc[4] = { {0,0,0,0}, {0,0,0,0}, {0,0,0,0}, {0,0,0,0} };
#pragma unroll
    for (int kc = 0; kc < K / 32; ++kc) {
        half8_t av = *(const half8_t*)(xrow + kc * 32);
#pragma unroll
        for (int c = 0; c < 4; ++c) {
            half8_t bv = *(const half8_t*)&wt[c * 16 + m][kc * 32 + q * 8];
            acc[c] = __builtin_amdgcn_mfma_f32_16x16x32_f16(av, bv, acc[c], 0, 0, 0);
        }
    }

#pragma unroll
    for (int r = 0; r < 4; ++r) {
        int row = row0 + wr + q * 4 + r;
        if (row < NN) {
#pragma unroll
            for (int c = 0; c < 4; ++c)
                H[(size_t)row * 64 + c * 16 + m] = (_Float16)acc[c][r];
        }
    }

    float as0 = a_src[m], as1 = a_src[16 + m], as2 = a_src[32 + m], as3 = a_src[48 + m];
    float ad0 = a_dst[m], ad1 = a_dst[16 + m], ad2 = a_dst[32 + m], ad3 = a_dst[48 + m];
#pragma unroll
    for (int r = 0; r < 4; ++r) {
        float s0 = acc[0][r] * as0 + acc[1][r] * as1;
        float s1 = acc[2][r] * as2 + acc[3][r] * as3;
        float d0 = acc[0][r] * ad0 + acc[1][r] * ad1;
        float d1 = acc[2][r] * ad2 + acc[3][r] * ad3;
#pragma unroll
        for (int mk = 1; mk < 16; mk <<= 1) {
            s0 += __shfl_xor(s0, mk);
            s1 += __shfl_xor(s1, mk);
            d0 += __shfl_xor(d0, mk);
            d1 += __shfl_xor(d1, mk);
        }
        int row = row0 + wr + q * 4 + r;
        if (m == 0 && row < NN) {
            asrc[2 * row + 0] = s0;
            asrc[2 * row + 1] = s1;
            adst[2 * row + 0] = d0;
            adst[2 * row + 1] = d1;
        }
    }
}

// ---------------- per-edge unnormalized softmax weights (edge-parallel) -------
__global__ __launch_bounds__(256) void edge_p(const int* __restrict__ esrc, const int* __restrict__ edst,
                                              const float* __restrict__ asrc, const float* __restrict__ adst,
                                              float2* __restrict__ pbuf) {
    int i = blockIdx.x * 256 + threadIdx.x;
    if (i >= TOTE) return;
    int s = esrc[i];
    int d = edst[i];
    float2 as = *(const float2*)(asrc + 2 * (size_t)s);
    float2 ad = *(const float2*)(adst + 2 * (size_t)d);
    float p0 = __expf(fminf(lrelu(as.x + ad.x), 60.f));
    float p1 = __expf(fminf(lrelu(as.y + ad.y), 60.f));
    pbuf[i] = make_float2(p0, p1);
}

// ---------------- edge aggregation: p-weighted gather + late normalize --------
// Wave per node. lane = eo*16 + c4: eo = edge slot (4-way), c4 = channel quad.
template <int MODE>
__global__ __launch_bounds__(256) void edge_agg(const int* __restrict__ dst_ptr, const int* __restrict__ esrc,
                                                const _Float16* __restrict__ h, const float* __restrict__ pbuf,
                                                const float* __restrict__ bias,
                                                const float* __restrict__ init_in, float* __restrict__ init_out,
                                                _Float16* __restrict__ xout) {
    int n = (blockIdx.x * 256 + threadIdx.x) >> 6;
    if (n >= NN) return;
    int lane = threadIdx.x & 63;
    int eo = lane >> 4;
    int c4 = lane & 15;
    int head = c4 >> 3;
    int rs = dst_ptr[n], re = dst_ptr[n + 1];
    const _Float16* hb = h + 4 * c4;
    const float* pb = pbuf + head;
    float a0 = 0.f, a1 = 0.f, a2 = 0.f, a3 = 0.f, lsum = 0.f;
    for (int i = rs; i < re; i += 8) {
        int iA = i + eo;
        int iB = i + 4 + eo;
        int cA = iA < re ? iA : re - 1;
        int cB = iB < re ? iB : re - 1;
        int sA = esrc[cA];
        int sB = esrc[cB];
        float wA = pb[2 * (size_t)cA];
        float wB = pb[2 * (size_t)cB];
        half4_t hA = *(const half4_t*)(hb + (size_t)sA * 64);
        half4_t hB = *(const half4_t*)(hb + (size_t)sB * 64);
        wA = iA < re ? wA : 0.f;
        wB = iB < re ? wB : 0.f;
        lsum += wA + wB;
        a0 += wA * (float)hA[0] + wB * (float)hB[0];
        a1 += wA * (float)hA[1] + wB * (float)hB[1];
        a2 += wA * (float)hA[2] + wB * (float)hB[2];
        a3 += wA * (float)hA[3] + wB * (float)hB[3];
    }
    // merge the 4 edge slots
    a0 += __shfl_xor(a0, 16); a1 += __shfl_xor(a1, 16);
    a2 += __shfl_xor(a2, 16); a3 += __shfl_xor(a3, 16);
    lsum += __shfl_xor(lsum, 16);
    a0 += __shfl_xor(a0, 32); a1 += __shfl_xor(a1, 32);
    a2 += __shfl_xor(a2, 32); a3 += __shfl_xor(a3, 32);
    lsum += __shfl_xor(lsum, 32);
    if (eo == 0) {
        float inv = 1.f / lsum;
        float4 bv = *(const float4*)(bias + 4 * c4);
        float t0 = a0 * inv + bv.x, t1 = a1 * inv + bv.y;
        float t2 = a2 * inv + bv.z, t3 = a3 * inv + bv.w;
        if (MODE == 0) {
            *(float4*)(init_out + (size_t)n * 64 + 4 * c4) = make_float4(t0, t1, t2, t3);
        } else {
            float4 iv = *(const float4*)(init_in + (size_t)n * 64 + 4 * c4);
            t0 += iv.x; t1 += iv.y; t2 += iv.z; t3 += iv.w;
        }
        t0 = t0 > 0.f ? t0 : __expf(t0) - 1.f;
        t1 = t1 > 0.f ? t1 : __expf(t1) - 1.f;
        t2 = t2 > 0.f ? t2 : __expf(t2) - 1.f;
        t3 = t3 > 0.f ? t3 : __expf(t3) - 1.f;
        half4_t o = { (_Float16)t0, (_Float16)t1, (_Float16)t2, (_Float16)t3 };
        *(half4_t*)(xout + (size_t)n * 64 + 4 * c4) = o;
    }
}

// ---------------- output layer ----------------
__global__ __launch_bounds__(256) void gemm_out_attn(const _Float16* __restrict__ x, const float* __restrict__ Wout,
                                                     const float* __restrict__ a_s, const float* __restrict__ a_d,
                                                     float* __restrict__ h_o, float* __restrict__ asrc_o,
                                                     float* __restrict__ adst_o) {
    int n = (blockIdx.x * 256 + threadIdx.x) >> 6;
    if (n >= NN) return;
    int lane = threadIdx.x & 63;
    float v = (float)x[n * 64 + lane] * Wout[lane];
    for (int m = 32; m >= 1; m >>= 1) v += __shfl_xor(v, m);
    if (lane == 0) {
        h_o[n] = v;
        asrc_o[n] = v * a_s[0];
        adst_o[n] = v * a_d[0];
    }
}

__global__ __launch_bounds__(256) void edge_agg_out(const int* __restrict__ dst_ptr, const int* __restrict__ esrc,
                                                    const float* __restrict__ h_o, const float* __restrict__ asrc_o,
                                                    const float* __restrict__ adst_o, const float* __restrict__ b_out,
                                                    float* __restrict__ out) {
    int n = (blockIdx.x * 256 + threadIdx.x) >> 6;
    if (n >= NN) return;
    int lane = threadIdx.x & 63;
    int rs = dst_ptr[n], re = dst_ptr[n + 1];
    float adv = adst_o[n];
    float l = 0.f, acc = 0.f;
    for (int i = rs + lane; i < re; i += 64) {
        int s = esrc[i];
        float e = fminf(lrelu(asrc_o[s] + adv), 60.f);
        float p = __expf(e);
        l += p;
        acc = fmaf(p, h_o[s], acc);
    }
    for (int mm = 32; mm >= 1; mm >>= 1) {
        l += __shfl_xor(l, mm);
        acc += __shfl_xor(acc, mm);
    }
    if (lane == 0) out[n] = 1.f / (1.f + __expf(-(acc / l + b_out[0])));
}

// ---------------- launch ----------------
extern "C" void kernel_launch(void* const* d_in, const int* in_sizes, int n_in,
                              void* d_out, int out_size, void* d_ws, size_t ws_size,
                              hipStream_t stream) {
    const float* node_attrs = (const float*)d_in[0];
    const int*   edge_index = (const int*)d_in[1];
    const float* W_in      = (const float*)d_in[2];
    const float* a_src_in  = (const float*)d_in[3];
    const float* a_dst_in  = (const float*)d_in[4];
    const float* b_in      = (const float*)d_in[5];
    const float* W_mid     = (const float*)d_in[6];
    const float* a_src_mid = (const float*)d_in[7];
    const float* a_dst_mid = (const float*)d_in[8];
    const float* b_mid     = (const float*)d_in[9];
    const float* W_out     = (const float*)d_in[10];
    const float* a_src_out = (const float*)d_in[11];
    const float* a_dst_out = (const float*)d_in[12];
    const float* b_out     = (const float*)d_in[13];
    float* out = (float*)d_out;

    const int* srcArr = edge_index;
    const int* dstArr = edge_index + EE;

    char* w = (char*)d_ws;
    auto alloc = [&](size_t bytes) { void* p = (void*)w; w += (bytes + 255) & ~(size_t)255; return p; };
    int*   dst_ptr    = (int*)alloc((size_t)(NN + 1) * 4);
    int*   gcur       = (int*)alloc((size_t)NBUK * 4);
    int*   bucketBase = (int*)alloc((size_t)(NBUK + 1) * 4);
    int*   region     = (int*)alloc((size_t)NBUK * CAPB * 4);
    int*   esrc       = (int*)alloc((size_t)TOTE * 4);
    int*   edst       = (int*)alloc((size_t)TOTE * 4);
    float2* pbuf      = (float2*)alloc((size_t)TOTE * 8);
    _Float16* xin16   = (_Float16*)alloc((size_t)NN * 128 * 2);
    _Float16* h       = (_Float16*)alloc((size_t)NN * 64 * 2);
    _Float16* x16     = (_Float16*)alloc((size_t)NN * 64 * 2);
    float* asrc       = (float*)alloc((size_t)NN * 2 * 4);
    float* adst       = (float*)alloc((size_t)NN * 2 * 4);
    float* ixbuf      = (float*)alloc((size_t)NN * 64 * 4);
    float* h_o        = (float*)alloc((size_t)NN * 4);
    float* asrc_o     = (float*)alloc((size_t)NN * 4);
    float* adst_o     = (float*)alloc((size_t)NN * 4);

    // CSR build
    hipMemsetAsync(gcur, 0, NBUK * 4, stream);
    binA<<<256, 256, 0, stream>>>(srcArr, dstArr, gcur, region);
    scan_buckets<<<1, 64, 0, stream>>>(gcur, bucketBase);
    binB<<<NBUK, 1024, 0, stream>>>(region, gcur, bucketBase, dst_ptr, esrc, edst);

    // cast node_attrs to f16
    int n4 = NN * 128 / 4;
    cast_x<<<(n4 + 255) / 256, 256, 0, stream>>>(node_attrs, xin16, n4);

    int gemmBlocks = (NN + 63) / 64;
    int nodeBlocks = (NN + 3) / 4;
    int edgeBlocks = (TOTE + 255) / 256;

    // input layer
    gemm_attn<128><<<gemmBlocks, 256, 0, stream>>>(xin16, W_in, a_src_in, a_dst_in, h, asrc, adst);
    edge_p<<<edgeBlocks, 256, 0, stream>>>(esrc, edst, asrc, adst, pbuf);
    edge_agg<0><<<nodeBlocks, 256, 0, stream>>>(dst_ptr, esrc, h, (const float*)pbuf, b_in, nullptr, ixbuf, x16);

    // 6 mid layers (shared weights)
    for (int l = 0; l < 6; ++l) {
        gemm_attn<64><<<gemmBlocks, 256, 0, stream>>>(x16, W_mid, a_src_mid, a_dst_mid, h, asrc, adst);
        edge_p<<<edgeBlocks, 256, 0, stream>>>(esrc, edst, asrc, adst, pbuf);
        edge_agg<1><<<nodeBlocks, 256, 0, stream>>>(dst_ptr, esrc, h, (const float*)pbuf, b_mid, ixbuf, nullptr, x16);
    }

    // output layer
    gemm_out_attn<<<nodeBlocks, 256, 0, stream>>>(x16, W_out, a_src_out, a_dst_out, h_o, asrc_o, adst_o);
    edge_agg_out<<<nodeBlocks, 256, 0, stream>>>(dst_ptr, esrc, h_o, asrc_o, adst_o, b_out, out);
}